// Round 11
// baseline (1750.894 us; speedup 1.0000x reference)
//
#include <hip/hip_runtime.h>

typedef unsigned short u16;
typedef unsigned int   u32;
typedef unsigned long long u64;
typedef short s8v __attribute__((ext_vector_type(8)));   // 8 bf16 (4 VGPRs)
typedef float f4v __attribute__((ext_vector_type(4)));   // 4 fp32 acc
typedef float f2v __attribute__((ext_vector_type(2)));   // packed fp32 pair
typedef int   i2v __attribute__((ext_vector_type(2)));
typedef unsigned long long ull2 __attribute__((ext_vector_type(2)));

#define STRIDE 168           // LDS A-row stride in elems (336B, 16B-aligned rows)
#define CAP 256              // ball-query cap (Poisson lambda~137, P(>256)~1e-24)
#define OFF_G1 0             // swizzled-weight elem offsets in ws (128 KiB total)
#define OFF_G2 12288
#define OFF_G3 28672
#define OFF_G4 49152

__device__ __forceinline__ float bf2f(u16 u){ return __uint_as_float(((u32)u)<<16); }
__device__ __forceinline__ u16 f2bf(float f){
  u32 u = __float_as_uint(f);
  return (u16)((u + 0x7FFFu + ((u>>16)&1u)) >> 16);      // RNE
}
// exact fp32, no-FMA, numpy order: (dx*dx + dy*dy) + dz*dz
__device__ __forceinline__ float sqd(float ax,float ay,float az,float bx,float by,float bz){
  float dx=ax-bx, dy=ay-by, dz=az-bz;
  return __fadd_rn(__fadd_rn(__fmul_rn(dx,dx),__fmul_rn(dy,dy)),__fmul_rn(dz,dz));
}

// DPP u32 max step (dist bits are positive floats -> unsigned == float ordering)
#define WMAX_STEP(v, CTRL) { \
  u32 _t = (u32)__builtin_amdgcn_update_dpp(0, (int)(v), CTRL, 0xf, 0xf, false); \
  (v) = (v) > _t ? (v) : _t; }

// ---------------------------------------------------------------- FPS (single wave)
// one wave per batch; 64 pts/lane in registers (lane L owns pts L*64..L*64+63,
// elem0 = pts 0..31 of the lane, elem1 = 32..63 -> order-preserving tie-break).
// No barrier, no cross-wave LDS merge: argmax = in-register payload tree + DPP.
__global__ __launch_bounds__(64,1) void fps_kernel(const float* __restrict__ xyz,
                                                   float* __restrict__ newxyz){
  __shared__ __align__(16) float SX[64][66], SY[64][66], SZ[64][66];  // 50.7 KB
  __shared__ __align__(16) float R[1024*3];                            // 12 KB
  const int b = blockIdx.x, lane = threadIdx.x;
  const float* xb = xyz + (size_t)b*4096*3;
  // stage: coalesced-ish global reads, LDS pt p -> S*[p>>6][p&63]
  for(int j=0;j<64;j++){
    int p = j*64 + lane;
    SX[j][lane] = xb[p*3]; SY[j][lane] = xb[p*3+1]; SZ[j][lane] = xb[p*3+2];
  }
  f2v X[32],Y[32],Z[32],DM[32];
  const float x0=SX[0][0], y0=SY[0][0], z0=SZ[0][0];
  {
    #pragma clang fp contract(off)
    const f2v fx2={x0,x0}, fy2={y0,y0}, fz2={z0,z0};
    #pragma unroll
    for(int k=0;k<32;k++){
      X[k] = (f2v){SX[lane][k], SX[lane][k+32]};
      Y[k] = (f2v){SY[lane][k], SY[lane][k+32]};
      Z[k] = (f2v){SZ[lane][k], SZ[lane][k+32]};
      f2v dx=X[k]-fx2, dy=Y[k]-fy2, dz=Z[k]-fz2;
      DM[k] = (dx*dx + dy*dy) + dz*dz;
    }
  }
  if(lane==0){ R[0]=x0; R[1]=y0; R[2]=z0; }
  for(int i=1;i<1024;i++){
    // payload tree argmax (strict >, adjacent pairing preserves index order)
    f2v v[32]; i2v ix[32];
    #pragma unroll
    for(int k=0;k<32;k++){ v[k]=DM[k]; ix[k]=(i2v){k, k+32}; }
    #pragma unroll
    for(int n=32;n>1;n>>=1)
      #pragma unroll
      for(int k=0;k<(n>>1);k++){
        i2v c = v[2*k+1] > v[2*k];          // strictly greater -> later wins
        v[k]  = c ? v[2*k+1] : v[2*k];
        ix[k] = c ? ix[2*k+1] : ix[2*k];
      }
    float vm; int jm;
    { bool g = v[0][1] > v[0][0]; vm = g ? v[0][1] : v[0][0]; jm = g ? ix[0][1] : ix[0][0]; }
    // wave max via DPP
    u32 w = __float_as_uint(vm);
    WMAX_STEP(w, 0x111); WMAX_STEP(w, 0x112); WMAX_STEP(w, 0x114);
    WMAX_STEP(w, 0x118); WMAX_STEP(w, 0x142); WMAX_STEP(w, 0x143);
    u32 wm = (u32)__builtin_amdgcn_readlane((int)w, 63);
    u64 msk = __ballot(__float_as_uint(vm) == wm);
    int ldr = __ffsll((unsigned long long)msk) - 1;    // min lane == min point idx
    int pj  = __builtin_amdgcn_readlane(jm, ldr);
    float fx=SX[ldr][pj], fy=SY[ldr][pj], fz=SZ[ldr][pj];  // uniform -> broadcast
    if(lane==0){ R[i*3]=fx; R[i*3+1]=fy; R[i*3+2]=fz; }
    {
      #pragma clang fp contract(off)
      const f2v fx2={fx,fx}, fy2={fy,fy}, fz2={fz,fz};
      #pragma unroll
      for(int k=0;k<32;k++){
        f2v dx=X[k]-fx2, dy=Y[k]-fy2, dz=Z[k]-fz2;
        f2v s = (dx*dx + dy*dy) + dz*dz;
        DM[k] = __builtin_elementwise_min(DM[k], s);
      }
    }
  }
  // coalesced dump: 3072 floats = 768 float4 by 64 lanes
  float* nb = newxyz + (size_t)b*3072;
  #pragma unroll
  for(int j=0;j<12;j++) ((float4*)nb)[j*64+lane] = ((const float4*)R)[j*64+lane];
}

// ---------------------------------------------------------------- ball query (standalone)
// one wave per sample; tiny LDS -> 8 blocks/CU hides gather latency.
// sel[32] ints stashed into the sample's fout slot (overwritten later by mlp).
__global__ __launch_bounds__(256) void ballq_kernel(const float* __restrict__ xyz,
                                                    const float* __restrict__ newxyz,
                                                    int* __restrict__ selg){
  __shared__ u64 Bc4[4][CAP+2];
  const int tid=threadIdx.x, wv=tid>>6, lane=tid&63;
  const int widx = blockIdx.x*4 + wv, b = widx>>10;
  const float* xb = xyz + (size_t)b*4096*3;
  const float cx=newxyz[widx*3], cy=newxyz[widx*3+1], cz=newxyz[widx*3+2];
  u64* Bc = Bc4[wv];
  int* selp = selg + (size_t)widx*128;
  const u64 lt = (1ull<<lane)-1ull;
  int base=0;
  for(int kk=0;kk<64;kk++){
    int p = kk*64 + lane;
    float d = sqd(cx,cy,cz, xb[p*3],xb[p*3+1],xb[p*3+2]);
    bool in = (d <= 0.04f);
    u64 m = __ballot(in);
    if(in){ int pos = base + __popcll(m&lt); if(pos<CAP) Bc[pos] = ((u64)__float_as_uint(d)<<32)|(u32)p; }
    base += __popcll(m);
  }
  int cnt = base>CAP ? CAP : base;
  if(cnt > 32){
    if(lane==0){ Bc[cnt]=~0ull; Bc[cnt+1]=~0ull; }     // sentinels (> any key)
    int cnt2 = (cnt+1)&~1;
    for(int c=lane; c<cnt; c+=64){
      u64 key = Bc[c]; int r=0;
      for(int t2=0;t2<cnt2;t2+=2){
        ull2 k2 = *(const ull2*)&Bc[t2];               // b128: 2 keys/read
        r += (k2[0] < key) ? 1 : 0;
        r += (k2[1] < key) ? 1 : 0;
      }
      if(r < 32) selp[r] = (int)(u32)key;              // low 32 = point index
    }
  } else {
    for(int c=lane; c<cnt; c+=64) selp[c] = (int)(u32)Bc[c];
    int need = 32 - cnt, b2 = 0;
    for(int kk=0; kk<64 && b2<need; kk++){
      int p = kk*64 + lane;
      float d = sqd(cx,cy,cz, xb[p*3],xb[p*3+1],xb[p*3+2]);
      bool o = !(d <= 0.04f);
      u64 m = __ballot(o);
      if(o){ int pos = b2 + __popcll(m&lt); if(pos<need) selp[cnt+pos] = p; }
      b2 += __popcll(m);
    }
  }
}

// ---------------------------------------------------------------- weight swizzle (f32 -> bf16 frags)
// B-frag-major: frag(c,t,lane) elem j = W[k'][t*16+(lane&15)], k'=c*32+(lane>>4)*8+j;
// G1/G3 row remap: 0..2 -> xyz rows, 3..31 -> zero, 32.. -> rows 3..
__global__ __launch_bounds__(256) void swz_kernel(const float* __restrict__ W1,const float* __restrict__ W2,
                                                  const float* __restrict__ W3,const float* __restrict__ W4,
                                                  u16* __restrict__ wsw){
  int T = blockIdx.x*256 + threadIdx.x;       // 8192 threads
  const float* W; int rel, base, kind;
  if(T < 1536){ rel=T;      base=OFF_G1; W=W1; kind=0; }
  else if(T < 3584){ rel=T-1536; base=OFF_G2; W=W2; kind=1; }
  else if(T < 6144){ rel=T-3584; base=OFF_G3; W=W3; kind=0; }
  else         { rel=T-6144; base=OFF_G4; W=W4; kind=1; }
  int chunk=rel>>6, lane=rel&63, c=chunk>>3, t=chunk&7, quad=lane>>4, l15=lane&15;
  u16 v[8];
  #pragma unroll
  for(int j=0;j<8;j++){
    int kp = c*32 + quad*8 + j, n = t*16 + l15;
    int src = (kind==0) ? (kp<3 ? kp : (kp>=32 ? kp-29 : -1)) : kp;
    v[j] = (src<0) ? (u16)0 : f2bf(W[src*128 + n]);
  }
  int4 o;
  o.x=(int)((u32)v[0]|((u32)v[1]<<16)); o.y=(int)((u32)v[2]|((u32)v[3]<<16));
  o.z=(int)((u32)v[4]|((u32)v[5]<<16)); o.w=(int)((u32)v[6]|((u32)v[7]<<16));
  *(int4*)&wsw[base + rel*8] = o;
}

// ---------------------------------------------------------------- MLP (gather + 4 GEMMs)
__device__ __forceinline__ void zero_C(f4v C[2][8]){
  #pragma unroll
  for(int mt=0;mt<2;mt++)
    #pragma unroll
    for(int t=0;t<8;t++) C[mt][t] = (f4v){0.f,0.f,0.f,0.f};
}
__device__ __forceinline__ void load_bias(const float* bsrc,int l15,float bb[8]){
  #pragma unroll
  for(int t=0;t<8;t++) bb[t]=bsrc[t*16+l15];
}
template<int KC>
__device__ __forceinline__ void run_gemm(const u16* A, const u16* BW,
                                         int lane,int l15,int quad, f4v C[2][8]){
  s8v af[2][KC];
  #pragma unroll
  for(int mt=0;mt<2;mt++)
    #pragma unroll
    for(int c=0;c<KC;c++)
      af[mt][c] = *(const s8v*)&A[(mt*16+l15)*STRIDE + c*32 + quad*8];
  #pragma unroll
  for(int t=0;t<8;t++){
    #pragma unroll
    for(int c=0;c<KC;c++){
      s8v bw = *(const s8v*)&BW[((c*8+t)*64 + lane)*8];
      C[0][t] = __builtin_amdgcn_mfma_f32_16x16x32_bf16(af[0][c],bw,C[0][t],0,0,0);
      C[1][t] = __builtin_amdgcn_mfma_f32_16x16x32_bf16(af[1][c],bw,C[1][t],0,0,0);
    }
  }
}
__device__ __forceinline__ void store_act(u16* A,int l15,int quad,f4v C[2][8],const float bb[8]){
  #pragma unroll
  for(int mt=0;mt<2;mt++)
    #pragma unroll
    for(int t=0;t<8;t++)
      #pragma unroll
      for(int r=0;r<4;r++){
        float v = fmaxf(C[mt][t][r]+bb[t], 0.f);
        A[(mt*16+quad*4+r)*STRIDE + t*16 + l15] = f2bf(v);
      }
}
__device__ __forceinline__ void write_xyz_chunk0(u16* A,int lane,float xn,float yn,float zn){
  if(lane<32){
    u16* row=&A[lane*STRIDE];
    row[0]=f2bf(xn); row[1]=f2bf(yn); row[2]=f2bf(zn); row[3]=0;
    #pragma unroll
    for(int q=0;q<7;q++) *(u64*)&row[4+q*4] = 0ull;   // cols 4..31 zero
  }
}

__global__ __launch_bounds__(256,3) void mlp_kernel(const float* __restrict__ xyz,
    const float* __restrict__ feats, const u16* __restrict__ wsw,
    const float* __restrict__ b1,const float* __restrict__ b2,const float* __restrict__ b3,const float* __restrict__ b4,
    const float* __restrict__ newxyz, float* __restrict__ fout){
  __shared__ __align__(16) u16 Abuf[4][32*STRIDE];
  const int tid=threadIdx.x, wv=tid>>6, lane=tid&63, quad=lane>>4, l15=lane&15;
  const int widx = blockIdx.x*4 + wv, b = widx>>10;
  u16* A = Abuf[wv];
  const float* xb = xyz + (size_t)b*4096*3;
  const float cx=newxyz[widx*3], cy=newxyz[widx*3+1], cz=newxyz[widx*3+2];
  // sel indices were stashed in this sample's fout slot by ballq_kernel
  const int* selp = (const int*)(fout + (size_t)widx*128);
  const int gi_f = selp[lane>>1] & 4095;
  const int gi_x = selp[lane & 31] & 4095;

  // ---- stage grouped features (f32 -> bf16) -> cols 32..95 ----
  {
    int r2=lane>>1, h=lane&1;
    const float* fs = feats + ((size_t)b*4096 + gi_f)*64 + h*32;
    u16* fd = &A[r2*STRIDE + 32 + h*32];
    #pragma unroll
    for(int j=0;j<8;j++){
      float4 v4 = ((const float4*)fs)[j];
      u64 pk4 = (u64)f2bf(v4.x) | ((u64)f2bf(v4.y)<<16)
              | ((u64)f2bf(v4.z)<<32) | ((u64)f2bf(v4.w)<<48);
      *(u64*)&fd[j*4] = pk4;
    }
  }
  // ---- grouped_xyz_norm -> chunk0 cols 0..2 (+ zero pad 3..31) ----
  float xn=0.f,yn=0.f,zn=0.f;
  if(lane<32){
    const float* xp = xb + (size_t)gi_x*3;
    xn = xp[0]-cx; yn = xp[1]-cy; zn = xp[2]-cz;
  }
  write_xyz_chunk0(A,lane,xn,yn,zn);
  __syncthreads();

  f4v C[2][8]; float bb[8];
  // GEMM1: f_in(32x96) @ W1 -> relu -> H1
  zero_C(C); load_bias(b1,l15,bb);
  run_gemm<3>(A, wsw+OFF_G1, lane,l15,quad, C);
  store_act(A,l15,quad,C,bb);
  __syncthreads();
  // GEMM2: H1 @ W2 -> relu -> f_prime
  zero_C(C); load_bias(b2,l15,bb);
  run_gemm<4>(A, wsw+OFF_G2, lane,l15,quad, C);
  float fp[2][8][4]; float mean[8];
  #pragma unroll
  for(int t=0;t<8;t++){
    float s=0.f;
    #pragma unroll
    for(int mt=0;mt<2;mt++)
      #pragma unroll
      for(int r=0;r<4;r++){
        float v = fmaxf(C[mt][t][r]+bb[t], 0.f);
        fp[mt][t][r]=v; s+=v;
      }
    s += __shfl_xor(s,16); s += __shfl_xor(s,32);
    mean[t] = s*0.03125f;
  }
  #pragma unroll
  for(int mt=0;mt<2;mt++)
    #pragma unroll
    for(int t=0;t<8;t++)
      #pragma unroll
      for(int r=0;r<4;r++)
        A[(mt*16+quad*4+r)*STRIDE + 32 + t*16 + l15] = f2bf(fp[mt][t][r]-mean[t]);
  write_xyz_chunk0(A,lane,xn,yn,zn);   // w_in chunk0
  __syncthreads();
  // GEMM3: w_in(32x160) @ W3 -> relu -> H3
  zero_C(C); load_bias(b3,l15,bb);
  run_gemm<5>(A, wsw+OFF_G3, lane,l15,quad, C);
  store_act(A,l15,quad,C,bb);
  __syncthreads();
  // GEMM4: H3 @ W4 -> sigmoid -> alpha; f_out = sum_k alpha*f_prime
  zero_C(C); load_bias(b4,l15,bb);
  run_gemm<4>(A, wsw+OFF_G4, lane,l15,quad, C);
  float* fo = fout + (size_t)widx*128;
  #pragma unroll
  for(int t=0;t<8;t++){
    float part=0.f;
    #pragma unroll
    for(int mt=0;mt<2;mt++)
      #pragma unroll
      for(int r=0;r<4;r++){
        float pre = C[mt][t][r]+bb[t];
        float a = 1.f/(1.f+__expf(-pre));
        part += a*fp[mt][t][r];
      }
    part += __shfl_xor(part,16); part += __shfl_xor(part,32);
    if(quad==0) fo[t*16+l15] = part;
  }
}

// ---------------------------------------------------------------- launch
extern "C" void kernel_launch(void* const* d_in, const int* in_sizes, int n_in,
                              void* d_out, int out_size, void* d_ws, size_t ws_size,
                              hipStream_t stream){
  (void)in_sizes; (void)n_in; (void)out_size; (void)ws_size;
  const float* xyz   = (const float*)d_in[0];
  const float* feats = (const float*)d_in[1];
  const float* W1 = (const float*)d_in[2]; const float* b1 = (const float*)d_in[3];
  const float* W2 = (const float*)d_in[4]; const float* b2 = (const float*)d_in[5];
  const float* W3 = (const float*)d_in[6]; const float* b3 = (const float*)d_in[7];
  const float* W4 = (const float*)d_in[8]; const float* b4 = (const float*)d_in[9];
  float* out = (float*)d_out;
  float* newxyz = out;               // (16,1024,3) f32
  float* fout   = out + 16*1024*3;   // (16,1024,128) f32 (sel stash, then result)
  u16* wsw = (u16*)d_ws;             // 128 KiB swizzled bf16 weights — only ws use

  hipLaunchKernelGGL(swz_kernel,   dim3(32),   dim3(256), 0, stream, W1,W2,W3,W4, wsw);
  hipLaunchKernelGGL(fps_kernel,   dim3(16),   dim3(64),  0, stream, xyz, newxyz);
  hipLaunchKernelGGL(ballq_kernel, dim3(4096), dim3(256), 0, stream, xyz, newxyz, (int*)fout);
  hipLaunchKernelGGL(mlp_kernel,   dim3(4096), dim3(256), 0, stream,
                     xyz, feats, wsw, b1,b2,b3,b4, newxyz, fout);
}

// Round 12
// 969.369 us; speedup vs baseline: 1.8062x; 1.8062x over previous
//
#include <hip/hip_runtime.h>

typedef unsigned short u16;
typedef unsigned int   u32;
typedef unsigned long long u64;
typedef short s8v __attribute__((ext_vector_type(8)));   // 8 bf16 (4 VGPRs)
typedef float f4v __attribute__((ext_vector_type(4)));   // 4 fp32 acc
typedef float f2v __attribute__((ext_vector_type(2)));   // packed fp32 pair
typedef unsigned long long ull2 __attribute__((ext_vector_type(2)));

#define STRIDE 168           // LDS A-row stride in elems (336B, 16B-aligned rows)
#define CAP 256              // ball-query cap (Poisson lambda~137, P(>256)~1e-24)
#define OFF_G1 0             // swizzled-weight elem offsets in ws (128 KiB total)
#define OFF_G2 12288
#define OFF_G3 28672
#define OFF_G4 49152

__device__ __forceinline__ float bf2f(u16 u){ return __uint_as_float(((u32)u)<<16); }
__device__ __forceinline__ u16 f2bf(float f){
  u32 u = __float_as_uint(f);
  return (u16)((u + 0x7FFFu + ((u>>16)&1u)) >> 16);      // RNE
}
// exact fp32, no-FMA, numpy order: (dx*dx + dy*dy) + dz*dz
__device__ __forceinline__ float sqd(float ax,float ay,float az,float bx,float by,float bz){
  float dx=ax-bx, dy=ay-by, dz=az-bz;
  return __fadd_rn(__fadd_rn(__fmul_rn(dx,dx),__fmul_rn(dy,dy)),__fmul_rn(dz,dz));
}

// DPP u32 max step (dist bits are positive floats -> unsigned == float ordering)
#define WMAX_STEP(v, CTRL) { \
  u32 _t = (u32)__builtin_amdgcn_update_dpp(0, (int)(v), CTRL, 0xf, 0xf, false); \
  (v) = (v) > _t ? (v) : _t; }
// u64 max step via DPP (all lanes valid with row_ror / quad_perm patterns)
#define QMAX64(k, CTRL) { \
  u32 _lo=(u32)(k), _hi=(u32)((k)>>32); \
  u32 _plo=(u32)__builtin_amdgcn_update_dpp(0,(int)_lo,CTRL,0xf,0xf,true); \
  u32 _phi=(u32)__builtin_amdgcn_update_dpp(0,(int)_hi,CTRL,0xf,0xf,true); \
  u64 _o=((u64)_phi<<32)|_plo; (k) = (k)>_o ? (k) : _o; }

// ---------------------------------------------------------------- FPS
// one block per batch; 8 waves (512 thr), 8 contiguous pts/thread (4 f2v —
// far from the VGPR spill cliff hit by the 1-wave/64-pt variant, R11).
// Merge: 8 packed u64 partials in LDS, row_ror:1/2/4 DPP all-reduce
// (red[lane&7] is period-8 within 16-lane rows -> rotate all-reduce exact).
__global__ __launch_bounds__(512) void fps_kernel(const float* __restrict__ xyz,
                                                  float* __restrict__ newxyz){
  __shared__ __align__(16) float S[4096*3];   // 48 KB points
  __shared__ __align__(16) float R[1024*3];   // 12 KB results
  __shared__ u64 red[2][8];
  const int b = blockIdx.x, tid = threadIdx.x;
  const int lane = tid & 63, wv = tid >> 6;
  const float* xb = xyz + (size_t)b*4096*3;
  #pragma unroll
  for(int j=0;j<6;j++) ((float4*)S)[j*512+tid] = ((const float4*)xb)[j*512+tid];
  __syncthreads();
  f2v X[4],Y[4],Z[4],DM[4];
  const float x0=S[0], y0=S[1], z0=S[2];
  {
    #pragma clang fp contract(off)
    const f2v fx2={x0,x0}, fy2={y0,y0}, fz2={z0,z0};
    #pragma unroll
    for(int k2=0;k2<4;k2++){
      int p0 = tid*8 + 2*k2;
      X[k2] = (f2v){S[p0*3],   S[p0*3+3]};
      Y[k2] = (f2v){S[p0*3+1], S[p0*3+4]};
      Z[k2] = (f2v){S[p0*3+2], S[p0*3+5]};
      f2v dx=X[k2]-fx2, dy=Y[k2]-fy2, dz=Z[k2]-fz2;
      DM[k2] = (dx*dx + dy*dy) + dz*dz;
    }
  }
  if(tid==0){ R[0]=x0; R[1]=y0; R[2]=z0; }
  for(int i=1;i<1024;i++){
    // value max: pk tree (depth 2) + horizontal
    f2v a = __builtin_elementwise_max(DM[0],DM[1]);
    f2v c = __builtin_elementwise_max(DM[2],DM[3]);
    f2v mm = __builtin_elementwise_max(a,c);
    float vm = fmaxf(mm[0], mm[1]);
    // first-occurrence local index via equality mask + ffs (bit j <-> pt j)
    u32 m8 = 0;
    #pragma unroll
    for(int j=0;j<8;j++) m8 |= (DM[j>>1][j&1]==vm) ? (1u<<j) : 0u;
    int jm = __ffs(m8)-1;
    // wave max via DPP (6 VALU steps), result in lane 63
    u32 w = __float_as_uint(vm);
    WMAX_STEP(w, 0x111); WMAX_STEP(w, 0x112); WMAX_STEP(w, 0x114);
    WMAX_STEP(w, 0x118); WMAX_STEP(w, 0x142); WMAX_STEP(w, 0x143);
    u32 wm = (u32)__builtin_amdgcn_readlane((int)w, 63);
    u64 msk = __ballot(__float_as_uint(vm) == wm);
    int ldr = __ffsll((unsigned long long)msk) - 1;
    int pj  = __builtin_amdgcn_readlane(jm, ldr);
    int p   = (wv*64 + ldr)*8 + pj;
    if(lane==0) red[i&1][wv] = ((u64)wm<<32) | (u32)(~(u32)p);
    __syncthreads();
    u64 k = red[i&1][lane&7];
    QMAX64(k, 0x121); QMAX64(k, 0x122); QMAX64(k, 0x124);   // row_ror 1,2,4
    int far = (int)(~(u32)k) & 4095;
    float fx=S[far*3], fy=S[far*3+1], fz=S[far*3+2];
    if(tid==0){ R[i*3]=fx; R[i*3+1]=fy; R[i*3+2]=fz; }
    {
      #pragma clang fp contract(off)
      const f2v fx2={fx,fx}, fy2={fy,fy}, fz2={fz,fz};
      #pragma unroll
      for(int k2c=0;k2c<4;k2c++){
        f2v dx=X[k2c]-fx2, dy=Y[k2c]-fy2, dz=Z[k2c]-fz2;
        f2v s = (dx*dx + dy*dy) + dz*dz;
        DM[k2c] = __builtin_elementwise_min(DM[k2c], s);
      }
    }
  }
  __syncthreads();
  // coalesced dump: 1024*3 floats = 768 float4 (first 384 threads do 2)
  float* nb = newxyz + (size_t)b*3072;
  if(tid<384){
    ((float4*)nb)[tid]     = ((const float4*)R)[tid];
    ((float4*)nb)[384+tid] = ((const float4*)R)[384+tid];
  }
}

// ---------------------------------------------------------------- ball query (standalone)
// one wave per sample; tiny LDS -> high occupancy hides gather latency.
// sel[32] ints stashed into the sample's fout slot (overwritten later by mlp).
__global__ __launch_bounds__(256) void ballq_kernel(const float* __restrict__ xyz,
                                                    const float* __restrict__ newxyz,
                                                    int* __restrict__ selg){
  __shared__ u64 Bc4[4][CAP+2];
  const int tid=threadIdx.x, wv=tid>>6, lane=tid&63;
  const int widx = blockIdx.x*4 + wv, b = widx>>10;
  const float* xb = xyz + (size_t)b*4096*3;
  const float cx=newxyz[widx*3], cy=newxyz[widx*3+1], cz=newxyz[widx*3+2];
  u64* Bc = Bc4[wv];
  int* selp = selg + (size_t)widx*128;
  const u64 lt = (1ull<<lane)-1ull;
  int base=0;
  for(int kk=0;kk<64;kk++){
    int p = kk*64 + lane;
    float d = sqd(cx,cy,cz, xb[p*3],xb[p*3+1],xb[p*3+2]);
    bool in = (d <= 0.04f);
    u64 m = __ballot(in);
    if(in){ int pos = base + __popcll(m&lt); if(pos<CAP) Bc[pos] = ((u64)__float_as_uint(d)<<32)|(u32)p; }
    base += __popcll(m);
  }
  int cnt = base>CAP ? CAP : base;
  if(cnt > 32){
    if(lane==0){ Bc[cnt]=~0ull; Bc[cnt+1]=~0ull; }     // sentinels (> any key)
    int cnt2 = (cnt+1)&~1;
    for(int c=lane; c<cnt; c+=64){
      u64 key = Bc[c]; int r=0;
      for(int t2=0;t2<cnt2;t2+=2){
        ull2 k2 = *(const ull2*)&Bc[t2];               // b128: 2 keys/read
        r += (k2[0] < key) ? 1 : 0;
        r += (k2[1] < key) ? 1 : 0;
      }
      if(r < 32) selp[r] = (int)(u32)key;              // low 32 = point index
    }
  } else {
    for(int c=lane; c<cnt; c+=64) selp[c] = (int)(u32)Bc[c];
    int need = 32 - cnt, b2 = 0;
    for(int kk=0; kk<64 && b2<need; kk++){
      int p = kk*64 + lane;
      float d = sqd(cx,cy,cz, xb[p*3],xb[p*3+1],xb[p*3+2]);
      bool o = !(d <= 0.04f);
      u64 m = __ballot(o);
      if(o){ int pos = b2 + __popcll(m&lt); if(pos<need) selp[cnt+pos] = p; }
      b2 += __popcll(m);
    }
  }
}

// ---------------------------------------------------------------- weight swizzle (f32 -> bf16 frags)
// B-frag-major: frag(c,t,lane) elem j = W[k'][t*16+(lane&15)], k'=c*32+(lane>>4)*8+j;
// G1/G3 row remap: 0..2 -> xyz rows, 3..31 -> zero, 32.. -> rows 3..
__global__ __launch_bounds__(256) void swz_kernel(const float* __restrict__ W1,const float* __restrict__ W2,
                                                  const float* __restrict__ W3,const float* __restrict__ W4,
                                                  u16* __restrict__ wsw){
  int T = blockIdx.x*256 + threadIdx.x;       // 8192 threads
  const float* W; int rel, base, kind;
  if(T < 1536){ rel=T;      base=OFF_G1; W=W1; kind=0; }
  else if(T < 3584){ rel=T-1536; base=OFF_G2; W=W2; kind=1; }
  else if(T < 6144){ rel=T-3584; base=OFF_G3; W=W3; kind=0; }
  else         { rel=T-6144; base=OFF_G4; W=W4; kind=1; }
  int chunk=rel>>6, lane=rel&63, c=chunk>>3, t=chunk&7, quad=lane>>4, l15=lane&15;
  u16 v[8];
  #pragma unroll
  for(int j=0;j<8;j++){
    int kp = c*32 + quad*8 + j, n = t*16 + l15;
    int src = (kind==0) ? (kp<3 ? kp : (kp>=32 ? kp-29 : -1)) : kp;
    v[j] = (src<0) ? (u16)0 : f2bf(W[src*128 + n]);
  }
  int4 o;
  o.x=(int)((u32)v[0]|((u32)v[1]<<16)); o.y=(int)((u32)v[2]|((u32)v[3]<<16));
  o.z=(int)((u32)v[4]|((u32)v[5]<<16)); o.w=(int)((u32)v[6]|((u32)v[7]<<16));
  *(int4*)&wsw[base + rel*8] = o;
}

// ---------------------------------------------------------------- MLP (gather + 4 GEMMs)
__device__ __forceinline__ void zero_C(f4v C[2][8]){
  #pragma unroll
  for(int mt=0;mt<2;mt++)
    #pragma unroll
    for(int t=0;t<8;t++) C[mt][t] = (f4v){0.f,0.f,0.f,0.f};
}
__device__ __forceinline__ void load_bias(const float* bsrc,int l15,float bb[8]){
  #pragma unroll
  for(int t=0;t<8;t++) bb[t]=bsrc[t*16+l15];
}
template<int KC>
__device__ __forceinline__ void run_gemm(const u16* A, const u16* BW,
                                         int lane,int l15,int quad, f4v C[2][8]){
  s8v af[2][KC];
  #pragma unroll
  for(int mt=0;mt<2;mt++)
    #pragma unroll
    for(int c=0;c<KC;c++)
      af[mt][c] = *(const s8v*)&A[(mt*16+l15)*STRIDE + c*32 + quad*8];
  #pragma unroll
  for(int t=0;t<8;t++){
    #pragma unroll
    for(int c=0;c<KC;c++){
      s8v bw = *(const s8v*)&BW[((c*8+t)*64 + lane)*8];
      C[0][t] = __builtin_amdgcn_mfma_f32_16x16x32_bf16(af[0][c],bw,C[0][t],0,0,0);
      C[1][t] = __builtin_amdgcn_mfma_f32_16x16x32_bf16(af[1][c],bw,C[1][t],0,0,0);
    }
  }
}
__device__ __forceinline__ void store_act(u16* A,int l15,int quad,f4v C[2][8],const float bb[8]){
  #pragma unroll
  for(int mt=0;mt<2;mt++)
    #pragma unroll
    for(int t=0;t<8;t++)
      #pragma unroll
      for(int r=0;r<4;r++){
        float v = fmaxf(C[mt][t][r]+bb[t], 0.f);
        A[(mt*16+quad*4+r)*STRIDE + t*16 + l15] = f2bf(v);
      }
}
__device__ __forceinline__ void write_xyz_chunk0(u16* A,int lane,float xn,float yn,float zn){
  if(lane<32){
    u16* row=&A[lane*STRIDE];
    row[0]=f2bf(xn); row[1]=f2bf(yn); row[2]=f2bf(zn); row[3]=0;
    #pragma unroll
    for(int q=0;q<7;q++) *(u64*)&row[4+q*4] = 0ull;   // cols 4..31 zero
  }
}

__global__ __launch_bounds__(256,3) void mlp_kernel(const float* __restrict__ xyz,
    const float* __restrict__ feats, const u16* __restrict__ wsw,
    const float* __restrict__ b1,const float* __restrict__ b2,const float* __restrict__ b3,const float* __restrict__ b4,
    const float* __restrict__ newxyz, float* __restrict__ fout){
  __shared__ __align__(16) u16 Abuf[4][32*STRIDE];
  const int tid=threadIdx.x, wv=tid>>6, lane=tid&63, quad=lane>>4, l15=lane&15;
  const int widx = blockIdx.x*4 + wv, b = widx>>10;
  u16* A = Abuf[wv];
  const float* xb = xyz + (size_t)b*4096*3;
  const float cx=newxyz[widx*3], cy=newxyz[widx*3+1], cz=newxyz[widx*3+2];
  // sel indices were stashed in this sample's fout slot by ballq_kernel
  const int* selp = (const int*)(fout + (size_t)widx*128);
  const int gi_f = selp[lane>>1] & 4095;
  const int gi_x = selp[lane & 31] & 4095;

  // ---- stage grouped features (f32 -> bf16) -> cols 32..95 ----
  {
    int r2=lane>>1, h=lane&1;
    const float* fs = feats + ((size_t)b*4096 + gi_f)*64 + h*32;
    u16* fd = &A[r2*STRIDE + 32 + h*32];
    #pragma unroll
    for(int j=0;j<8;j++){
      float4 v4 = ((const float4*)fs)[j];
      u64 pk4 = (u64)f2bf(v4.x) | ((u64)f2bf(v4.y)<<16)
              | ((u64)f2bf(v4.z)<<32) | ((u64)f2bf(v4.w)<<48);
      *(u64*)&fd[j*4] = pk4;
    }
  }
  // ---- grouped_xyz_norm -> chunk0 cols 0..2 (+ zero pad 3..31) ----
  float xn=0.f,yn=0.f,zn=0.f;
  if(lane<32){
    const float* xp = xb + (size_t)gi_x*3;
    xn = xp[0]-cx; yn = xp[1]-cy; zn = xp[2]-cz;
  }
  write_xyz_chunk0(A,lane,xn,yn,zn);
  __syncthreads();

  f4v C[2][8]; float bb[8];
  // GEMM1: f_in(32x96) @ W1 -> relu -> H1
  zero_C(C); load_bias(b1,l15,bb);
  run_gemm<3>(A, wsw+OFF_G1, lane,l15,quad, C);
  store_act(A,l15,quad,C,bb);
  __syncthreads();
  // GEMM2: H1 @ W2 -> relu -> f_prime
  zero_C(C); load_bias(b2,l15,bb);
  run_gemm<4>(A, wsw+OFF_G2, lane,l15,quad, C);
  float fp[2][8][4]; float mean[8];
  #pragma unroll
  for(int t=0;t<8;t++){
    float s=0.f;
    #pragma unroll
    for(int mt=0;mt<2;mt++)
      #pragma unroll
      for(int r=0;r<4;r++){
        float v = fmaxf(C[mt][t][r]+bb[t], 0.f);
        fp[mt][t][r]=v; s+=v;
      }
    s += __shfl_xor(s,16); s += __shfl_xor(s,32);
    mean[t] = s*0.03125f;
  }
  #pragma unroll
  for(int mt=0;mt<2;mt++)
    #pragma unroll
    for(int t=0;t<8;t++)
      #pragma unroll
      for(int r=0;r<4;r++)
        A[(mt*16+quad*4+r)*STRIDE + 32 + t*16 + l15] = f2bf(fp[mt][t][r]-mean[t]);
  write_xyz_chunk0(A,lane,xn,yn,zn);   // w_in chunk0
  __syncthreads();
  // GEMM3: w_in(32x160) @ W3 -> relu -> H3
  zero_C(C); load_bias(b3,l15,bb);
  run_gemm<5>(A, wsw+OFF_G3, lane,l15,quad, C);
  store_act(A,l15,quad,C,bb);
  __syncthreads();
  // GEMM4: H3 @ W4 -> sigmoid -> alpha; f_out = sum_k alpha*f_prime
  zero_C(C); load_bias(b4,l15,bb);
  run_gemm<4>(A, wsw+OFF_G4, lane,l15,quad, C);
  float* fo = fout + (size_t)widx*128;
  #pragma unroll
  for(int t=0;t<8;t++){
    float part=0.f;
    #pragma unroll
    for(int mt=0;mt<2;mt++)
      #pragma unroll
      for(int r=0;r<4;r++){
        float pre = C[mt][t][r]+bb[t];
        float a = 1.f/(1.f+__expf(-pre));
        part += a*fp[mt][t][r];
      }
    part += __shfl_xor(part,16); part += __shfl_xor(part,32);
    if(quad==0) fo[t*16+l15] = part;
  }
}

// ---------------------------------------------------------------- launch
extern "C" void kernel_launch(void* const* d_in, const int* in_sizes, int n_in,
                              void* d_out, int out_size, void* d_ws, size_t ws_size,
                              hipStream_t stream){
  (void)in_sizes; (void)n_in; (void)out_size; (void)ws_size;
  const float* xyz   = (const float*)d_in[0];
  const float* feats = (const float*)d_in[1];
  const float* W1 = (const float*)d_in[2]; const float* b1 = (const float*)d_in[3];
  const float* W2 = (const float*)d_in[4]; const float* b2 = (const float*)d_in[5];
  const float* W3 = (const float*)d_in[6]; const float* b3 = (const float*)d_in[7];
  const float* W4 = (const float*)d_in[8]; const float* b4 = (const float*)d_in[9];
  float* out = (float*)d_out;
  float* newxyz = out;               // (16,1024,3) f32
  float* fout   = out + 16*1024*3;   // (16,1024,128) f32 (sel stash, then result)
  u16* wsw = (u16*)d_ws;             // 128 KiB swizzled bf16 weights — only ws use

  hipLaunchKernelGGL(swz_kernel,   dim3(32),   dim3(256), 0, stream, W1,W2,W3,W4, wsw);
  hipLaunchKernelGGL(fps_kernel,   dim3(16),   dim3(512), 0, stream, xyz, newxyz);
  hipLaunchKernelGGL(ballq_kernel, dim3(4096), dim3(256), 0, stream, xyz, newxyz, (int*)fout);
  hipLaunchKernelGGL(mlp_kernel,   dim3(4096), dim3(256), 0, stream,
                     xyz, feats, wsw, b1,b2,b3,b4, newxyz, fout);
}